// Round 9
// baseline (638.746 us; speedup 1.0000x reference)
//
#include <hip/hip_runtime.h>

// Shapes fixed by the reference setup.
#define BB 32
#define HH 16
#define NN 1024
#define DD 128

// R9: read-once structure. 256 persistent blocks x 256 threads (cooperative
// launch, all co-resident: <=1 block/CU even at worst-case VGPR). Each block
// processes 8 quarter-rows (256 n x 128 d = 128 KB) over 8 iterations:
//   load quarter into 32 named float4/thread (128 VGPR payload; 256-thread
//   block => 4 waves => VGPR budget 256 via __launch_bounds__(256,2) — the
//   1024-thread versions (R7/R8) were capped at 128 VGPR and HAD to spill),
//   compute own-masked local softmax stats (m,z,lmin), exchange 3 words/quarter
//   via agent-scope atomics + per-row release counter, spin-acquire for the
//   row's 4 quarters, combine -> padd/M/S, scale held registers, store.
// t is read from HBM exactly once; no second pass through the ~3.15 TB/s
// read path (the model fitting R0-R8: reads cap ~3.15 TB/s from HBM or L3,
// writes ~6.4 TB/s and overlap).
// Deadlock-free: at iteration g, row 64g+m is handled by blocks 4m..4m+3,
// all at the same iteration index; all 256 blocks are co-resident.

#define FOR32(M) M(0) M(1) M(2) M(3) M(4) M(5) M(6) M(7) \
                 M(8) M(9) M(10) M(11) M(12) M(13) M(14) M(15) \
                 M(16) M(17) M(18) M(19) M(20) M(21) M(22) M(23) \
                 M(24) M(25) M(26) M(27) M(28) M(29) M(30) M(31)

#define FORPAIRS(M) M(0,1) M(2,3) M(4,5) M(6,7) M(8,9) M(10,11) M(12,13) \
                    M(14,15) M(16,17) M(18,19) M(20,21) M(22,23) M(24,25) \
                    M(26,27) M(28,29) M(30,31)

#define AGENT __HIP_MEMORY_SCOPE_AGENT

__global__ __launch_bounds__(256, 2) void fused_kernel(const float* __restrict__ t,
                                                       const int* __restrict__ padding,
                                                       const float* __restrict__ w2,
                                                       float* __restrict__ out,
                                                       float* __restrict__ exch,
                                                       int* __restrict__ flags) {
    const int j    = blockIdx.x;        // 0..255
    const int tid  = threadIdx.x;       // 0..255
    const int wid  = tid >> 6;          // wave 0..3
    const int lane = tid & 63;
    const int hw   = tid >> 5;          // half-wave 0..7
    const int l    = tid & 31;

    __shared__ float s_sc[256];         // this quarter's scores by n_loc
    __shared__ float s_fac[256];        // this quarter's factors
    __shared__ float red_m[4];
    __shared__ float red_z[4];
    __shared__ int   red_i[4];
    __shared__ float s_ex[12];          // 4 quarters x (m, z, lmin)

    const float4 wv = ((const float4*)w2)[l];
    const float  NEG = -3.4e38f;

    for (int g = 0; g < 8; ++g) {
        const int q   = g * 256 + j;    // quarter id 0..2047
        const int row = q >> 2;         // bh 0..511
        const int qi  = q & 3;          // quarter within row
        const int b   = row >> 4;       // H = 16

        // ---- load quarter: thread holds n_loc = k*8 + hw, float4-col l ----
        const float4* base = (const float4*)(t + (long)row * (NN * DD) + (long)qi * (256 * DD));
#define DECLV(K) float4 v##K;
        FOR32(DECLV)
#undef DECLV
#define LOADV(K) v##K = base[(K) * 256 + tid];
        FOR32(LOADV)
#undef LOADV

        // ---- local first-zero of padding slice (own-mask) ----
        int pl = (padding[b * NN + qi * 256 + tid] == 0) ? tid : 256;
#pragma unroll
        for (int off = 32; off; off >>= 1) pl = min(pl, __shfl_xor(pl, off));
        if (lane == 0) red_i[wid] = pl;

        // ---- dots + pair-merged butterfly -> s_sc[n_loc] ----
#define PAIR(K0, K1) {                                                        \
            const float a  = v##K0.x * wv.x + v##K0.y * wv.y                  \
                           + v##K0.z * wv.z + v##K0.w * wv.w;                 \
            const float bq = v##K1.x * wv.x + v##K1.y * wv.y                  \
                           + v##K1.z * wv.z + v##K1.w * wv.w;                 \
            float x = (l < 16) ? a : bq;                                      \
            float y = (l < 16) ? bq : a;                                      \
            x += __shfl_xor(y, 16);                                           \
            x += __shfl_xor(x, 8);                                            \
            x += __shfl_xor(x, 4);                                            \
            x += __shfl_xor(x, 2);                                            \
            x += __shfl_xor(x, 1);                                            \
            if (l == 0)  s_sc[(K0) * 8 + hw] = x;                             \
            if (l == 16) s_sc[(K1) * 8 + hw] = x;                             \
        }
        FORPAIRS(PAIR)
#undef PAIR
        __syncthreads();                 // red_i + s_sc ready

        const int lmin = min(min(red_i[0], red_i[1]), min(red_i[2], red_i[3]));

        // ---- own-masked local max ----
        const float sc = s_sc[tid];      // n_loc = tid
        float mm = (tid < lmin) ? sc : NEG;
#pragma unroll
        for (int off = 32; off; off >>= 1) mm = fmaxf(mm, __shfl_xor(mm, off));
        if (lane == 0) red_m[wid] = mm;
        __syncthreads();
        const float lm = fmaxf(fmaxf(red_m[0], red_m[1]), fmaxf(red_m[2], red_m[3]));

        // ---- own-masked local sum of exp(s - lm) ----
        const float e = (tid < lmin) ? __expf(sc - lm) : 0.f;
        float z = e;
#pragma unroll
        for (int off = 32; off; off >>= 1) z += __shfl_xor(z, off);
        if (lane == 0) red_z[wid] = z;
        __syncthreads();
        const float lz = red_z[0] + red_z[1] + red_z[2] + red_z[3];

        // ---- publish (m, z, lmin) + release-count ----
        if (tid == 0) {
            float* ex = exch + (long)(row * 4 + qi) * 4;
            __hip_atomic_store(&ex[0], lm, __ATOMIC_RELAXED, AGENT);
            __hip_atomic_store(&ex[1], lz, __ATOMIC_RELAXED, AGENT);
            __hip_atomic_store(&ex[2], (float)lmin, __ATOMIC_RELAXED, AGENT);
            __hip_atomic_fetch_add(&flags[row], 1, __ATOMIC_RELEASE, AGENT);
            // ---- spin until all 4 quarters posted ----
            while (__hip_atomic_load(&flags[row], __ATOMIC_ACQUIRE, AGENT) < 4) {
                __builtin_amdgcn_s_sleep(8);
            }
        }
        __syncthreads();                 // all threads ordered after t0's acquire

        if (tid < 12) {
            const int qq = tid / 3, w = tid % 3;
            s_ex[tid] = __hip_atomic_load(exch + (long)(row * 4 + qq) * 4 + w,
                                          __ATOMIC_RELAXED, AGENT);
        }
        __syncthreads();

        // ---- combine: padd, M, S (every thread, 4 values) ----
        int padd = NN;
#pragma unroll
        for (int qq = 0; qq < 4; ++qq) {
            const int lq = (int)s_ex[qq * 3 + 2];
            if (lq < 256) { padd = min(padd, qq * 256 + lq); }
        }
        float M = NEG;
#pragma unroll
        for (int qq = 0; qq < 4; ++qq)
            if (qq * 256 < padd) M = fmaxf(M, s_ex[qq * 3 + 0]);
        float S = 0.f;
#pragma unroll
        for (int qq = 0; qq < 4; ++qq)
            if (qq * 256 < padd) S += s_ex[qq * 3 + 1] * __expf(s_ex[qq * 3 + 0] - M);

        // ---- factor for own n (n_glob = qi*256 + tid) ----
        float f = 1.f;
        if (qi * 256 + tid < padd && S > 0.f)
            f = 1.f + (e * __expf(lm - M)) / S;
        s_fac[tid] = f;
        __syncthreads();

        // ---- scale held registers, store ----
        float4* obase = (float4*)(out + (long)row * (NN * DD) + (long)qi * (256 * DD));
#define ST(K) {                                                               \
            const float ff = s_fac[(K) * 8 + hw];                             \
            float4 w = v##K;                                                  \
            w.x *= ff; w.y *= ff; w.z *= ff; w.w *= ff;                       \
            obase[(K) * 256 + tid] = w;                                       \
        }
        FOR32(ST)
#undef ST
        __syncthreads();                 // LDS reuse guard for next iteration
    }
}

extern "C" void kernel_launch(void* const* d_in, const int* in_sizes, int n_in,
                              void* d_out, int out_size, void* d_ws, size_t ws_size,
                              hipStream_t stream) {
    // inputs: 0 t_1 (unused — softmax shift-invariance), 1 t, 2 padding, 3 N,
    //         4 concat_w (w1 unused | w2), 5 concat_b (unused — cancels)
    const float* t       = (const float*)d_in[1];
    const int*   padding = (const int*)d_in[2];
    const float* w2p     = (const float*)d_in[4] + DD;
    float*       out     = (float*)d_out;
    float*       exch    = (float*)d_ws;                       // 512*4*4 floats = 32 KB
    int*         flags   = (int*)((char*)d_ws + 512 * 4 * 4 * sizeof(float)); // 2 KB

    hipMemsetAsync(d_ws, 0, 512 * 4 * 4 * sizeof(float) + 512 * sizeof(int), stream);

    void* args[] = { (void*)&t, (void*)&padding, (void*)&w2p, (void*)&out,
                     (void*)&exch, (void*)&flags };
    hipLaunchCooperativeKernel((const void*)fused_kernel, dim3(256), dim3(256),
                               args, 0, stream);
}